// Round 5
// baseline (1837.395 us; speedup 1.0000x reference)
//
#include <hip/hip_runtime.h>
#include <hip/hip_bf16.h>

// GIPA wide conv: h=XWn; e=EWe; score=leaky(dot_head(h[src],e)/sqrt(32));
// softmax over dst; out = segsum(h[src]*attn).
// R5: DIAGNOSTIC ROUND (correctness-preserving ablation-by-repetition).
// The three big kernels are pure -> rep-looping them is idempotent.
//   k_node_proj x4, k_edge_score x8, k_aggregate x16.
// Purpose: (1) surface our kernels above the 120us harness fills in the top-5
// counter table; (2) solve per-kernel times from dur_us = base + 3Tnp + 7Tes + 15Tag.
// Structure otherwise identical to R4.

#define NN 50000
#define NE 800000

#define REP_NP 4
#define REP_ES 8
#define REP_AG 16

typedef __bf16 bf16x8 __attribute__((ext_vector_type(8)));
typedef float f32x4 __attribute__((ext_vector_type(4)));

static __device__ __forceinline__ f32x4 mfma16(bf16x8 a, bf16x8 b, f32x4 c) {
  return __builtin_amdgcn_mfma_f32_16x16x32_bf16(a, b, c, 0, 0, 0);
}

static __device__ __forceinline__ bf16x8 cvt8(const float* p) {
  float4 a = *(const float4*)p;
  float4 b = *(const float4*)(p + 4);
  bf16x8 r;
  r[0] = (__bf16)a.x; r[1] = (__bf16)a.y; r[2] = (__bf16)a.z; r[3] = (__bf16)a.w;
  r[4] = (__bf16)b.x; r[5] = (__bf16)b.y; r[6] = (__bf16)b.z; r[7] = (__bf16)b.w;
  return r;
}

// ---- K0: transpose + fp32->bf16 weights, and zero deg ----
__global__ __launch_bounds__(256) void k_transpose_w(const float* __restrict__ Wn,
                                                     const float* __restrict__ We,
                                                     __bf16* __restrict__ WtN,
                                                     __bf16* __restrict__ WtE,
                                                     int* __restrict__ deg) {
  int t = blockIdx.x * 256 + threadIdx.x;             // 160*256 = 40960 threads
  if (t < 128 * 256) {
    int col = t >> 8, k = t & 255;
    WtN[t] = (__bf16)Wn[k * 128 + col];
  } else {
    int o = t - 128 * 256;            // 0..8191
    int col = o >> 6, k = o & 63;
    WtE[o] = (__bf16)We[k * 128 + col];
  }
  for (int i = t; i < NN; i += 40960) deg[i] = 0;
}

// ---- K1: node projection h[NN][128] bf16 via MFMA (REP_NP idempotent reps) ----
__global__ __launch_bounds__(256) void k_node_proj(const float* __restrict__ nf,
                                                   const __bf16* __restrict__ WtN,
                                                   __bf16* __restrict__ h) {
  int tid = threadIdx.x;
  int w = tid >> 6, lane = tid & 63, q = lane >> 4, c = lane & 15;
  int colbase = w * 32;
  bf16x8 bf[2][8];
#pragma unroll
  for (int nt = 0; nt < 2; ++nt)
#pragma unroll
    for (int ks = 0; ks < 8; ++ks)
      bf[nt][ks] = *(const bf16x8*)&WtN[(colbase + nt * 16 + c) * 256 + ks * 32 + q * 8];

  for (int rep = 0; rep < REP_NP; ++rep)
  for (int g = 0; g < 5; ++g) {
    int gbase = (blockIdx.x * 5 + g) * 16;            // exact: 625*5*16 = 50000
    const float* arow = nf + (size_t)(gbase + c) * 256 + q * 8;
    bf16x8 af[8];
#pragma unroll
    for (int ks = 0; ks < 8; ++ks) af[ks] = cvt8(arow + ks * 32);
    f32x4 acc0 = {0.f, 0.f, 0.f, 0.f}, acc1 = acc0;
#pragma unroll
    for (int ks = 0; ks < 8; ++ks) {
      acc0 = mfma16(af[ks], bf[0][ks], acc0);
      acc1 = mfma16(af[ks], bf[1][ks], acc1);
    }
#pragma unroll
    for (int reg = 0; reg < 4; ++reg) {
      int node = gbase + q * 4 + reg;
      h[(size_t)node * 128 + colbase + c]      = (__bf16)acc0[reg];
      h[(size_t)node * 128 + colbase + 16 + c] = (__bf16)acc1[reg];
    }
  }
}

// ---- K2: degree histogram (grid-stride @2048) ----
__global__ __launch_bounds__(256) void k_degree(const int* __restrict__ dst, int* __restrict__ deg) {
  for (int e = blockIdx.x * 256 + threadIdx.x; e < NE; e += 2048 * 256)
    atomicAdd(&deg[dst[e]], 1);
}

// ---- K3: single-block exclusive scan -> rowptr, fill ----
__global__ __launch_bounds__(256) void k_scan_all(const int* __restrict__ deg,
                                                  int* __restrict__ rowptr,
                                                  int* __restrict__ fill) {
  int t = threadIdx.x;
  int base = t * 196;
  const int4* d4 = (const int4*)deg;
  int i40 = base >> 2;

  int sum = 0;
#pragma unroll 1
  for (int k = 0; k < 49; ++k) {
    int i4 = i40 + k;
    if (i4 < (NN >> 2)) {
      int4 v = d4[i4];
      sum += v.x + v.y + v.z + v.w;
    }
  }

  __shared__ int s[256];
  s[t] = sum;
  __syncthreads();
  for (int off = 1; off < 256; off <<= 1) {
    int x = (t >= off) ? s[t - off] : 0;
    __syncthreads();
    s[t] += x;
    __syncthreads();
  }
  int run = s[t] - sum;

  int4* r4 = (int4*)rowptr;
  int4* f4 = (int4*)fill;
#pragma unroll 1
  for (int k = 0; k < 49; ++k) {
    int i4 = i40 + k;
    if (i4 < (NN >> 2)) {
      int4 v = d4[i4];
      int4 o;
      o.x = run;
      o.y = run + v.x;
      o.z = o.y + v.y;
      o.w = o.z + v.z;
      run = o.w + v.w;
      r4[i4] = o;
      f4[i4] = o;
    }
  }
  if (t == 255) rowptr[NN] = NE;
}

// ---- K4: scatter edge ids by dst (grid-stride @2048) ----
__global__ __launch_bounds__(256) void k_scatter(const int* __restrict__ dst, int* __restrict__ fill,
                                                 int* __restrict__ eids) {
  for (int e = blockIdx.x * 256 + threadIdx.x; e < NE; e += 2048 * 256) {
    int p = atomicAdd(&fill[dst[e]], 1);
    eids[p] = e;
  }
}

// ---- K5: fused edge projection + score (REP_ES idempotent reps) ----
__global__ __launch_bounds__(256) void k_edge_score(const float* __restrict__ ef,
                                                    const __bf16* __restrict__ WtE,
                                                    const __bf16* __restrict__ h,
                                                    const int* __restrict__ src,
                                                    float* __restrict__ score) {
  int tid = threadIdx.x;
  int w = tid >> 6, lane = tid & 63, q = lane >> 4, c = lane & 15;
  __shared__ float elds[4][16][132];
  const unsigned int* h2 = (const unsigned int*)h;

  bf16x8 bf[8][2];
#pragma unroll
  for (int nt = 0; nt < 8; ++nt)
#pragma unroll
    for (int ks = 0; ks < 2; ++ks)
      bf[nt][ks] = *(const bf16x8*)&WtE[(nt * 16 + c) * 64 + ks * 32 + q * 8];

  int el = lane >> 2;
  int head = lane & 3;

  for (int rep = 0; rep < REP_ES; ++rep)
  for (int it = blockIdx.x; it < 12500; it += gridDim.x) {
    int ebase = it * 64 + w * 16;                     // 12500*64 = 800000
    const float* arow = ef + (size_t)(ebase + c) * 64 + q * 8;
    bf16x8 af0 = cvt8(arow);
    bf16x8 af1 = cvt8(arow + 32);

    int sr = src[ebase + el];
    const uint4* hrow = (const uint4*)(h2 + (size_t)sr * 64 + head * 16);
    uint4 hv0 = hrow[0], hv1 = hrow[1], hv2 = hrow[2], hv3 = hrow[3];

    f32x4 acc[8];
#pragma unroll
    for (int nt = 0; nt < 8; ++nt) acc[nt] = (f32x4){0.f, 0.f, 0.f, 0.f};
#pragma unroll
    for (int nt = 0; nt < 8; ++nt) acc[nt] = mfma16(af0, bf[nt][0], acc[nt]);
#pragma unroll
    for (int nt = 0; nt < 8; ++nt) acc[nt] = mfma16(af1, bf[nt][1], acc[nt]);

#pragma unroll
    for (int nt = 0; nt < 8; ++nt)
#pragma unroll
      for (int reg = 0; reg < 4; ++reg)
        elds[w][q * 4 + reg][nt * 16 + c] = acc[nt][reg];
    asm volatile("s_waitcnt lgkmcnt(0)" ::: "memory");
    __builtin_amdgcn_sched_barrier(0);

    const float* erow = &elds[w][el][head * 32];
    float s = 0.f;
    union { unsigned int i; float f; } u0, u1;
#define DOT2(hd, ea, eb) \
    u0.i = (hd) << 16; u1.i = (hd) & 0xffff0000u; \
    s = fmaf(u0.f, (ea), s); s = fmaf(u1.f, (eb), s);
    {
      float4 e0 = *(const float4*)(erow +  0), e1 = *(const float4*)(erow +  4);
      float4 e2 = *(const float4*)(erow +  8), e3 = *(const float4*)(erow + 12);
      DOT2(hv0.x, e0.x, e0.y) DOT2(hv0.y, e0.z, e0.w)
      DOT2(hv0.z, e1.x, e1.y) DOT2(hv0.w, e1.z, e1.w)
      DOT2(hv1.x, e2.x, e2.y) DOT2(hv1.y, e2.z, e2.w)
      DOT2(hv1.z, e3.x, e3.y) DOT2(hv1.w, e3.z, e3.w)
    }
    {
      float4 e4 = *(const float4*)(erow + 16), e5 = *(const float4*)(erow + 20);
      float4 e6 = *(const float4*)(erow + 24), e7 = *(const float4*)(erow + 28);
      DOT2(hv2.x, e4.x, e4.y) DOT2(hv2.y, e4.z, e4.w)
      DOT2(hv2.z, e5.x, e5.y) DOT2(hv2.w, e5.z, e5.w)
      DOT2(hv3.x, e6.x, e6.y) DOT2(hv3.y, e6.z, e6.w)
      DOT2(hv3.z, e7.x, e7.y) DOT2(hv3.w, e7.z, e7.w)
    }
#undef DOT2

    s *= 0.17677669529663687f;
    float sv = s > 0.f ? s : 0.01f * s;
    score[(size_t)ebase * 4 + lane] = sv;
    __builtin_amdgcn_sched_barrier(0);
  }
}

// ---- K6: per-node softmax + aggregation (REP_AG idempotent reps) ----
__global__ __launch_bounds__(256) void k_aggregate(const int* __restrict__ rowptr,
                                                   const int* __restrict__ eids,
                                                   const int* __restrict__ src,
                                                   const float* __restrict__ score,
                                                   const __bf16* __restrict__ h,
                                                   float* __restrict__ out) {
  int w = threadIdx.x >> 6, lane = threadIdx.x & 63;
  int head = lane >> 4;
  int je = lane & 15;
  int hb = head << 4;
  const unsigned int* h2 = (const unsigned int*)h;

  for (int rep = 0; rep < REP_AG; ++rep)
  for (int grp = blockIdx.x; grp < 12500; grp += gridDim.x) {
    int n = grp * 4 + w;
    int s0 = rowptr[n], s1 = rowptr[n + 1];

    float l = 0.f, a0 = 0.f, a1 = 0.f;

    for (int c0 = s0; c0 < s1; c0 += 16) {
      int nc = s1 - c0; if (nc > 16) nc = 16;
      int srl = 0;
      float p = 0.f;
      if (je < nc) {
        int el = eids[c0 + je];
        srl = src[el];
        p = __expf(score[(size_t)el * 4 + head]);
      }
      float ps = p;
      ps += __shfl_xor(ps, 1, 64);
      ps += __shfl_xor(ps, 2, 64);
      ps += __shfl_xor(ps, 4, 64);
      ps += __shfl_xor(ps, 8, 64);
      l += ps;

      uint4 A, B;
#define LOADG(D, base) { int sr_; \
      sr_ = __shfl(srl, (base) + 0, 64); D.x = h2[(size_t)sr_ * 64 + lane]; \
      sr_ = __shfl(srl, (base) + 1, 64); D.y = h2[(size_t)sr_ * 64 + lane]; \
      sr_ = __shfl(srl, (base) + 2, 64); D.z = h2[(size_t)sr_ * 64 + lane]; \
      sr_ = __shfl(srl, (base) + 3, 64); D.w = h2[(size_t)sr_ * 64 + lane]; }
#define CONS(D, base) { float pj_; union { unsigned int i; float f; } u0_, u1_; \
      pj_ = __shfl(p, hb + (base) + 0, 64); u0_.i = D.x << 16; u1_.i = D.x & 0xffff0000u; a0 = fmaf(pj_, u0_.f, a0); a1 = fmaf(pj_, u1_.f, a1); \
      pj_ = __shfl(p, hb + (base) + 1, 64); u0_.i = D.y << 16; u1_.i = D.y & 0xffff0000u; a0 = fmaf(pj_, u0_.f, a0); a1 = fmaf(pj_, u1_.f, a1); \
      pj_ = __shfl(p, hb + (base) + 2, 64); u0_.i = D.z << 16; u1_.i = D.z & 0xffff0000u; a0 = fmaf(pj_, u0_.f, a0); a1 = fmaf(pj_, u1_.f, a1); \
      pj_ = __shfl(p, hb + (base) + 3, 64); u0_.i = D.w << 16; u1_.i = D.w & 0xffff0000u; a0 = fmaf(pj_, u0_.f, a0); a1 = fmaf(pj_, u1_.f, a1); }

      LOADG(A, 0);
      if (nc > 4) {
        LOADG(B, 4);
        CONS(A, 0);
        if (nc > 8) {
          LOADG(A, 8);
          CONS(B, 4);
          if (nc > 12) {
            LOADG(B, 12);
            CONS(A, 8);
            CONS(B, 12);
          } else {
            CONS(A, 8);
          }
        } else {
          CONS(B, 4);
        }
      } else {
        CONS(A, 0);
      }
#undef LOADG
#undef CONS
    }
    float inv = (s1 > s0) ? 1.f / l : 0.f;
    float2 o; o.x = a0 * inv; o.y = a1 * inv;
    ((float2*)out)[(size_t)n * 64 + lane] = o;
  }
}

extern "C" void kernel_launch(void* const* d_in, const int* in_sizes, int n_in,
                              void* d_out, int out_size, void* d_ws, size_t ws_size,
                              hipStream_t stream) {
  const float* node_feat = (const float*)d_in[0];   // [NN,256] fp32
  const float* edge_feat = (const float*)d_in[1];   // [NE,64]  fp32
  const int*   src       = (const int*)d_in[2];
  const int*   dst       = (const int*)d_in[3];
  const float* W_node    = (const float*)d_in[4];   // [256,128] fp32
  const float* W_edge    = (const float*)d_in[5];   // [64,128]  fp32
  float* out             = (float*)d_out;           // [NN,128] fp32

  char* ws = (char*)d_ws;
  __bf16* h      = (__bf16*)(ws + 0);               // 12,800,000
  float*  score  = (float*) (ws + 12800000);        // 12,800,000
  int*    eids   = (int*)   (ws + 25600000);        //  3,200,000
  int*    deg    = (int*)   (ws + 28800000);        //    200,000
  int*    rowptr = (int*)   (ws + 29000192);        //    200,004
  int*    fill   = (int*)   (ws + 29200640);        //    200,000
  __bf16* WtN    = (__bf16*)(ws + 29402880);        //     65,536
  __bf16* WtE    = (__bf16*)(ws + 29468416);        //     16,384

  k_transpose_w<<<160, 256, 0, stream>>>(W_node, W_edge, WtN, WtE, deg);
  k_node_proj  <<<625, 256, 0, stream>>>(node_feat, WtN, h);
  k_degree     <<<2048, 256, 0, stream>>>(dst, deg);
  k_scan_all   <<<1, 256, 0, stream>>>(deg, rowptr, fill);
  k_scatter    <<<2048, 256, 0, stream>>>(dst, fill, eids);
  k_edge_score <<<768, 256, 0, stream>>>(edge_feat, WtE, h, src, score);
  k_aggregate  <<<2048, 256, 0, stream>>>(rowptr, eids, src, score, h, out);
}

// Round 7
// 483.143 us; speedup vs baseline: 3.8030x; 3.8030x over previous
//
#include <hip/hip_runtime.h>
#include <hip/hip_bf16.h>

// GIPA wide conv: h=XWn; e=EWe; score=leaky(dot_head(h[src],e)/sqrt(32));
// softmax over dst; out = segsum(h[src]*attn).
// R7 == R6 resubmit (container infra failure, no measurement).
// R6: latency-hiding fusion. Per R5 diagnostic: T_ag~58, T_es~55, T_np~22,
// smalls ~60-90, ~300us harness-fixed. Changes:
//  - degree atomics interleaved into node_proj's MFMA loop (exact 800k map)
//  - scatter interleaved into edge_score's first 5 iterations (exact 800k map)
//  - scan_all: 1024 threads, pipelined 13x int4/thread (was serial 49/thread)
//  - edge_score stores exp(score); aggregate skips expf
//  - aggregate: 16 h-row loads in flight, branchless tail (row-0 dummies, p=0)
// 5 dispatches total.

#define NN 50000
#define NE 800000

typedef __bf16 bf16x8 __attribute__((ext_vector_type(8)));
typedef float f32x4 __attribute__((ext_vector_type(4)));

static __device__ __forceinline__ f32x4 mfma16(bf16x8 a, bf16x8 b, f32x4 c) {
  return __builtin_amdgcn_mfma_f32_16x16x32_bf16(a, b, c, 0, 0, 0);
}

static __device__ __forceinline__ bf16x8 cvt8(const float* p) {
  float4 a = *(const float4*)p;
  float4 b = *(const float4*)(p + 4);
  bf16x8 r;
  r[0] = (__bf16)a.x; r[1] = (__bf16)a.y; r[2] = (__bf16)a.z; r[3] = (__bf16)a.w;
  r[4] = (__bf16)b.x; r[5] = (__bf16)b.y; r[6] = (__bf16)b.z; r[7] = (__bf16)b.w;
  return r;
}

// ---- K0: transpose + fp32->bf16 weights, zero deg ----
__global__ __launch_bounds__(256) void k_transpose_w(const float* __restrict__ Wn,
                                                     const float* __restrict__ We,
                                                     __bf16* __restrict__ WtN,
                                                     __bf16* __restrict__ WtE,
                                                     int* __restrict__ deg) {
  int t = blockIdx.x * 256 + threadIdx.x;             // 160*256 = 40960 threads
  if (t < 128 * 256) {
    int col = t >> 8, k = t & 255;
    WtN[t] = (__bf16)Wn[k * 128 + col];
  } else {
    int o = t - 128 * 256;            // 0..8191
    int col = o >> 6, k = o & 63;
    WtE[o] = (__bf16)We[k * 128 + col];
  }
  for (int i = t; i < NN; i += 40960) deg[i] = 0;
}

// ---- K1: node projection + degree histogram (atomic hides under MFMA) ----
// Exact mapping: (blockIdx*5+g)*256+tid covers [0,800000) once.
__global__ __launch_bounds__(256) void k_node_proj_deg(const float* __restrict__ nf,
                                                       const __bf16* __restrict__ WtN,
                                                       __bf16* __restrict__ h,
                                                       const int* __restrict__ dst,
                                                       int* __restrict__ deg) {
  int tid = threadIdx.x;
  int w = tid >> 6, lane = tid & 63, q = lane >> 4, c = lane & 15;
  int colbase = w * 32;
  bf16x8 bf[2][8];
#pragma unroll
  for (int nt = 0; nt < 2; ++nt)
#pragma unroll
    for (int ks = 0; ks < 8; ++ks)
      bf[nt][ks] = *(const bf16x8*)&WtN[(colbase + nt * 16 + c) * 256 + ks * 32 + q * 8];

  for (int g = 0; g < 5; ++g) {
    int gi = blockIdx.x * 5 + g;
    int gbase = gi * 16;                              // exact: 625*5*16 = 50000
    // degree edge for this iteration (latency hidden under MFMA below)
    int e_d = gi * 256 + tid;                         // exact: 625*5*256 = 800000
    int dv = dst[e_d];

    const float* arow = nf + (size_t)(gbase + c) * 256 + q * 8;
    bf16x8 af[8];
#pragma unroll
    for (int ks = 0; ks < 8; ++ks) af[ks] = cvt8(arow + ks * 32);

    atomicAdd(&deg[dv], 1);

    f32x4 acc0 = {0.f, 0.f, 0.f, 0.f}, acc1 = acc0;
#pragma unroll
    for (int ks = 0; ks < 8; ++ks) {
      acc0 = mfma16(af[ks], bf[0][ks], acc0);
      acc1 = mfma16(af[ks], bf[1][ks], acc1);
    }
#pragma unroll
    for (int reg = 0; reg < 4; ++reg) {
      int node = gbase + q * 4 + reg;
      h[(size_t)node * 128 + colbase + c]      = (__bf16)acc0[reg];
      h[(size_t)node * 128 + colbase + 16 + c] = (__bf16)acc1[reg];
    }
  }
}

// ---- K2: single-block exclusive scan (1024 thr, 13 int4 each, pipelined) ----
__global__ __launch_bounds__(1024) void k_scan_all(const int* __restrict__ deg,
                                                   int* __restrict__ rowptr,
                                                   int* __restrict__ fill) {
  int t = threadIdx.x;
  const int4* d4 = (const int4*)deg;
  int i40 = t * 13;                   // 1024*13 = 13312 >= 12500 = NN/4
  int4 v[13];
#pragma unroll
  for (int k = 0; k < 13; ++k) {
    int i4 = i40 + k;
    if (i4 < (NN >> 2)) v[k] = d4[i4];
  }
  int sum = 0;
#pragma unroll
  for (int k = 0; k < 13; ++k) {
    int i4 = i40 + k;
    if (i4 < (NN >> 2)) sum += v[k].x + v[k].y + v[k].z + v[k].w;
  }
  __shared__ int s[1024];
  s[t] = sum;
  __syncthreads();
  for (int off = 1; off < 1024; off <<= 1) {
    int x = (t >= off) ? s[t - off] : 0;
    __syncthreads();
    s[t] += x;
    __syncthreads();
  }
  int run = s[t] - sum;               // exclusive base
  int4* r4 = (int4*)rowptr;
  int4* f4 = (int4*)fill;
#pragma unroll
  for (int k = 0; k < 13; ++k) {
    int i4 = i40 + k;
    if (i4 < (NN >> 2)) {
      int4 vv = v[k];
      int4 o;
      o.x = run;
      o.y = run + vv.x;
      o.z = o.y + vv.y;
      o.w = o.z + vv.z;
      run = o.w + vv.w;
      r4[i4] = o;
      f4[i4] = o;
    }
  }
  if (t == 0) rowptr[NN] = NE;
}

// ---- K3: fused edge projection + score (stores exp) + scatter ----
// Scatter carried by first 5 local iterations: (blockIdx*5+L)*256+tid covers
// [0,800000) exactly over blocks 0..624; guard kills the rest. Atomic+store
// latency hides under MFMA + LDS round-trip.
__global__ __launch_bounds__(256) void k_edge_score_scatter(const float* __restrict__ ef,
                                                            const __bf16* __restrict__ WtE,
                                                            const __bf16* __restrict__ h,
                                                            const int* __restrict__ src,
                                                            const int* __restrict__ dst,
                                                            int* __restrict__ fill,
                                                            int* __restrict__ eids,
                                                            float* __restrict__ expsc) {
  int tid = threadIdx.x;
  int w = tid >> 6, lane = tid & 63, q = lane >> 4, c = lane & 15;
  __shared__ float elds[4][16][132];
  const unsigned int* h2 = (const unsigned int*)h;

  bf16x8 bf[8][2];
#pragma unroll
  for (int nt = 0; nt < 8; ++nt)
#pragma unroll
    for (int ks = 0; ks < 2; ++ks)
      bf[nt][ks] = *(const bf16x8*)&WtE[(nt * 16 + c) * 64 + ks * 32 + q * 8];

  int el = lane >> 2;
  int head = lane & 3;

  int L = 0;
  for (int it = blockIdx.x; it < 12500; it += 768, ++L) {
    // scatter carry (blocks 0..624, L<5): hidden under the work below
    if (L < 5) {
      int e_sc = (blockIdx.x * 5 + L) * 256 + tid;
      if (e_sc < NE) {
        int p = atomicAdd(&fill[dst[e_sc]], 1);
        eids[p] = e_sc;
      }
    }

    int ebase = it * 64 + w * 16;                     // 12500*64 = 800000
    const float* arow = ef + (size_t)(ebase + c) * 64 + q * 8;
    bf16x8 af0 = cvt8(arow);
    bf16x8 af1 = cvt8(arow + 32);

    int sr = src[ebase + el];
    const uint4* hrow = (const uint4*)(h2 + (size_t)sr * 64 + head * 16);
    uint4 hv0 = hrow[0], hv1 = hrow[1], hv2 = hrow[2], hv3 = hrow[3];

    f32x4 acc[8];
#pragma unroll
    for (int nt = 0; nt < 8; ++nt) acc[nt] = (f32x4){0.f, 0.f, 0.f, 0.f};
#pragma unroll
    for (int nt = 0; nt < 8; ++nt) acc[nt] = mfma16(af0, bf[nt][0], acc[nt]);
#pragma unroll
    for (int nt = 0; nt < 8; ++nt) acc[nt] = mfma16(af1, bf[nt][1], acc[nt]);

#pragma unroll
    for (int nt = 0; nt < 8; ++nt)
#pragma unroll
      for (int reg = 0; reg < 4; ++reg)
        elds[w][q * 4 + reg][nt * 16 + c] = acc[nt][reg];
    asm volatile("s_waitcnt lgkmcnt(0)" ::: "memory");
    __builtin_amdgcn_sched_barrier(0);

    const float* erow = &elds[w][el][head * 32];
    float s = 0.f;
    union { unsigned int i; float f; } u0, u1;
#define DOT2(hd, ea, eb) \
    u0.i = (hd) << 16; u1.i = (hd) & 0xffff0000u; \
    s = fmaf(u0.f, (ea), s); s = fmaf(u1.f, (eb), s);
    {
      float4 e0 = *(const float4*)(erow +  0), e1 = *(const float4*)(erow +  4);
      float4 e2 = *(const float4*)(erow +  8), e3 = *(const float4*)(erow + 12);
      DOT2(hv0.x, e0.x, e0.y) DOT2(hv0.y, e0.z, e0.w)
      DOT2(hv0.z, e1.x, e1.y) DOT2(hv0.w, e1.z, e1.w)
      DOT2(hv1.x, e2.x, e2.y) DOT2(hv1.y, e2.z, e2.w)
      DOT2(hv1.z, e3.x, e3.y) DOT2(hv1.w, e3.z, e3.w)
    }
    {
      float4 e4 = *(const float4*)(erow + 16), e5 = *(const float4*)(erow + 20);
      float4 e6 = *(const float4*)(erow + 24), e7 = *(const float4*)(erow + 28);
      DOT2(hv2.x, e4.x, e4.y) DOT2(hv2.y, e4.z, e4.w)
      DOT2(hv2.z, e5.x, e5.y) DOT2(hv2.w, e5.z, e5.w)
      DOT2(hv3.x, e6.x, e6.y) DOT2(hv3.y, e6.z, e6.w)
      DOT2(hv3.z, e7.x, e7.y) DOT2(hv3.w, e7.z, e7.w)
    }
#undef DOT2

    s *= 0.17677669529663687f;        // 1/sqrt(32)
    float sv = s > 0.f ? s : 0.01f * s;
    // store exp(leaky(score)) directly — aggregate skips expf entirely.
    // sv is O(+-20) -> exp finite in fp32; ratios identical (no max-sub, as R3).
    expsc[(size_t)ebase * 4 + lane] = __expf(sv);
    __builtin_amdgcn_sched_barrier(0);
  }
}

// ---- K4: per-node softmax + aggregation (grid-stride @2048) ----
// 16-edge chunks; lane = (head, je). p read pre-exp'd. Branchless: all 16
// h-row loads issued unconditionally (pads use row 0, killed by p=0) ->
// 16 loads in flight per wave (2x prior MLP depth).
__global__ __launch_bounds__(256) void k_aggregate(const int* __restrict__ rowptr,
                                                   const int* __restrict__ eids,
                                                   const int* __restrict__ src,
                                                   const float* __restrict__ expsc,
                                                   const __bf16* __restrict__ h,
                                                   float* __restrict__ out) {
  int w = threadIdx.x >> 6, lane = threadIdx.x & 63;
  int head = lane >> 4;
  int je = lane & 15;
  int hb = head << 4;
  const unsigned int* h2 = (const unsigned int*)h;

  for (int grp = blockIdx.x; grp < 12500; grp += gridDim.x) {
    int n = grp * 4 + w;                              // 12500*4 = 50000
    int s0 = rowptr[n], s1 = rowptr[n + 1];

    float l = 0.f, a0 = 0.f, a1 = 0.f;

    for (int c0 = s0; c0 < s1; c0 += 16) {
      int nc = s1 - c0; if (nc > 16) nc = 16;
      int srl = 0;
      float p = 0.f;
      if (je < nc) {
        int el = eids[c0 + je];
        srl = src[el];
        p = expsc[(size_t)el * 4 + head];
      }
      float ps = p;
      ps += __shfl_xor(ps, 1, 64);
      ps += __shfl_xor(ps, 2, 64);
      ps += __shfl_xor(ps, 4, 64);
      ps += __shfl_xor(ps, 8, 64);
      l += ps;

      uint4 A, B, C, D;
#define LOADG(Dv, base) { int sr_; \
      sr_ = __shfl(srl, (base) + 0, 64); Dv.x = h2[(size_t)sr_ * 64 + lane]; \
      sr_ = __shfl(srl, (base) + 1, 64); Dv.y = h2[(size_t)sr_ * 64 + lane]; \
      sr_ = __shfl(srl, (base) + 2, 64); Dv.z = h2[(size_t)sr_ * 64 + lane]; \
      sr_ = __shfl(srl, (base) + 3, 64); Dv.w = h2[(size_t)sr_ * 64 + lane]; }
#define CONS(Dv, base) { float pj_; union { unsigned int i; float f; } u0_, u1_; \
      pj_ = __shfl(p, hb + (base) + 0, 64); u0_.i = Dv.x << 16; u1_.i = Dv.x & 0xffff0000u; a0 = fmaf(pj_, u0_.f, a0); a1 = fmaf(pj_, u1_.f, a1); \
      pj_ = __shfl(p, hb + (base) + 1, 64); u0_.i = Dv.y << 16; u1_.i = Dv.y & 0xffff0000u; a0 = fmaf(pj_, u0_.f, a0); a1 = fmaf(pj_, u1_.f, a1); \
      pj_ = __shfl(p, hb + (base) + 2, 64); u0_.i = Dv.z << 16; u1_.i = Dv.z & 0xffff0000u; a0 = fmaf(pj_, u0_.f, a0); a1 = fmaf(pj_, u1_.f, a1); \
      pj_ = __shfl(p, hb + (base) + 3, 64); u0_.i = Dv.w << 16; u1_.i = Dv.w & 0xffff0000u; a0 = fmaf(pj_, u0_.f, a0); a1 = fmaf(pj_, u1_.f, a1); }

      LOADG(A, 0); LOADG(B, 4); LOADG(C, 8); LOADG(D, 12);
      CONS(A, 0); CONS(B, 4); CONS(C, 8); CONS(D, 12);
#undef LOADG
#undef CONS
    }
    float inv = (s1 > s0) ? 1.f / l : 0.f;
    float2 o; o.x = a0 * inv; o.y = a1 * inv;
    ((float2*)out)[(size_t)n * 64 + lane] = o;
  }
}

extern "C" void kernel_launch(void* const* d_in, const int* in_sizes, int n_in,
                              void* d_out, int out_size, void* d_ws, size_t ws_size,
                              hipStream_t stream) {
  const float* node_feat = (const float*)d_in[0];   // [NN,256] fp32
  const float* edge_feat = (const float*)d_in[1];   // [NE,64]  fp32
  const int*   src       = (const int*)d_in[2];
  const int*   dst       = (const int*)d_in[3];
  const float* W_node    = (const float*)d_in[4];   // [256,128] fp32
  const float* W_edge    = (const float*)d_in[5];   // [64,128]  fp32
  float* out             = (float*)d_out;           // [NN,128] fp32

  char* ws = (char*)d_ws;
  __bf16* h      = (__bf16*)(ws + 0);               // 12,800,000
  float*  expsc  = (float*) (ws + 12800000);        // 12,800,000
  int*    eids   = (int*)   (ws + 25600000);        //  3,200,000
  int*    deg    = (int*)   (ws + 28800000);        //    200,000
  int*    rowptr = (int*)   (ws + 29000192);        //    200,004
  int*    fill   = (int*)   (ws + 29200640);        //    200,000
  __bf16* WtN    = (__bf16*)(ws + 29402880);        //     65,536
  __bf16* WtE    = (__bf16*)(ws + 29468416);        //     16,384

  k_transpose_w       <<<160, 256, 0, stream>>>(W_node, W_edge, WtN, WtE, deg);
  k_node_proj_deg     <<<625, 256, 0, stream>>>(node_feat, WtN, h, dst, deg);
  k_scan_all          <<<1, 1024, 0, stream>>>(deg, rowptr, fill);
  k_edge_score_scatter<<<768, 256, 0, stream>>>(edge_feat, WtE, h, src, dst, fill, eids, expsc);
  k_aggregate         <<<2048, 256, 0, stream>>>(rowptr, eids, src, expsc, h, out);
}

// Round 8
// 477.917 us; speedup vs baseline: 3.8446x; 1.0109x over previous
//
#include <hip/hip_runtime.h>
#include <hip/hip_bf16.h>

// GIPA wide conv: h=XWn; e=EWe; score=leaky(dot_head(h[src],e)/sqrt(32));
// softmax over dst; out = segsum(h[src]*attn).
// R8: gather-chain latency attack (R5/R7 diagnosis: both big kernels are
// dependent-gather latency-bound, neither pipe saturated).
//  - scatter writes srcs_sorted[p]=src[e]: ag's src read becomes coalesced,
//    issued parallel with eids -> h-loads issue ~400cy earlier
//  - ag: chunk-meta software pipeline (next eids/srcs/expsc under CONS)
//  - es: cross-iteration prefetch of ef row + src (sr register-resident at
//    iteration top -> h-gather issues immediately); sched_barriers/asm removed
//    (per-wave DS ordering suffices; lets compiler pipeline);
//    __launch_bounds__(256,3) pins 3 blocks/CU for the 768 grid.
// 5 dispatches.

#define NN 50000
#define NE 800000

typedef __bf16 bf16x8 __attribute__((ext_vector_type(8)));
typedef float f32x4 __attribute__((ext_vector_type(4)));

static __device__ __forceinline__ f32x4 mfma16(bf16x8 a, bf16x8 b, f32x4 c) {
  return __builtin_amdgcn_mfma_f32_16x16x32_bf16(a, b, c, 0, 0, 0);
}

static __device__ __forceinline__ bf16x8 cvt8(const float* p) {
  float4 a = *(const float4*)p;
  float4 b = *(const float4*)(p + 4);
  bf16x8 r;
  r[0] = (__bf16)a.x; r[1] = (__bf16)a.y; r[2] = (__bf16)a.z; r[3] = (__bf16)a.w;
  r[4] = (__bf16)b.x; r[5] = (__bf16)b.y; r[6] = (__bf16)b.z; r[7] = (__bf16)b.w;
  return r;
}

static __device__ __forceinline__ bf16x8 cvt8p(float4 a, float4 b) {
  bf16x8 r;
  r[0] = (__bf16)a.x; r[1] = (__bf16)a.y; r[2] = (__bf16)a.z; r[3] = (__bf16)a.w;
  r[4] = (__bf16)b.x; r[5] = (__bf16)b.y; r[6] = (__bf16)b.z; r[7] = (__bf16)b.w;
  return r;
}

// ---- K0: transpose + fp32->bf16 weights, zero deg ----
__global__ __launch_bounds__(256) void k_transpose_w(const float* __restrict__ Wn,
                                                     const float* __restrict__ We,
                                                     __bf16* __restrict__ WtN,
                                                     __bf16* __restrict__ WtE,
                                                     int* __restrict__ deg) {
  int t = blockIdx.x * 256 + threadIdx.x;             // 160*256 = 40960 threads
  if (t < 128 * 256) {
    int col = t >> 8, k = t & 255;
    WtN[t] = (__bf16)Wn[k * 128 + col];
  } else {
    int o = t - 128 * 256;            // 0..8191
    int col = o >> 6, k = o & 63;
    WtE[o] = (__bf16)We[k * 128 + col];
  }
  for (int i = t; i < NN; i += 40960) deg[i] = 0;
}

// ---- K1: node projection + degree histogram (atomic hides under MFMA) ----
__global__ __launch_bounds__(256) void k_node_proj_deg(const float* __restrict__ nf,
                                                       const __bf16* __restrict__ WtN,
                                                       __bf16* __restrict__ h,
                                                       const int* __restrict__ dst,
                                                       int* __restrict__ deg) {
  int tid = threadIdx.x;
  int w = tid >> 6, lane = tid & 63, q = lane >> 4, c = lane & 15;
  int colbase = w * 32;
  bf16x8 bf[2][8];
#pragma unroll
  for (int nt = 0; nt < 2; ++nt)
#pragma unroll
    for (int ks = 0; ks < 8; ++ks)
      bf[nt][ks] = *(const bf16x8*)&WtN[(colbase + nt * 16 + c) * 256 + ks * 32 + q * 8];

  for (int g = 0; g < 5; ++g) {
    int gi = blockIdx.x * 5 + g;
    int gbase = gi * 16;                              // exact: 625*5*16 = 50000
    int e_d = gi * 256 + tid;                         // exact: 625*5*256 = 800000
    int dv = dst[e_d];

    const float* arow = nf + (size_t)(gbase + c) * 256 + q * 8;
    bf16x8 af[8];
#pragma unroll
    for (int ks = 0; ks < 8; ++ks) af[ks] = cvt8(arow + ks * 32);

    atomicAdd(&deg[dv], 1);

    f32x4 acc0 = {0.f, 0.f, 0.f, 0.f}, acc1 = acc0;
#pragma unroll
    for (int ks = 0; ks < 8; ++ks) {
      acc0 = mfma16(af[ks], bf[0][ks], acc0);
      acc1 = mfma16(af[ks], bf[1][ks], acc1);
    }
#pragma unroll
    for (int reg = 0; reg < 4; ++reg) {
      int node = gbase + q * 4 + reg;
      h[(size_t)node * 128 + colbase + c]      = (__bf16)acc0[reg];
      h[(size_t)node * 128 + colbase + 16 + c] = (__bf16)acc1[reg];
    }
  }
}

// ---- K2: single-block exclusive scan (1024 thr, 13 int4 each) ----
__global__ __launch_bounds__(1024) void k_scan_all(const int* __restrict__ deg,
                                                   int* __restrict__ rowptr,
                                                   int* __restrict__ fill) {
  int t = threadIdx.x;
  const int4* d4 = (const int4*)deg;
  int i40 = t * 13;                   // 1024*13 = 13312 >= 12500 = NN/4
  int4 v[13];
#pragma unroll
  for (int k = 0; k < 13; ++k) {
    int i4 = i40 + k;
    if (i4 < (NN >> 2)) v[k] = d4[i4];
  }
  int sum = 0;
#pragma unroll
  for (int k = 0; k < 13; ++k) {
    int i4 = i40 + k;
    if (i4 < (NN >> 2)) sum += v[k].x + v[k].y + v[k].z + v[k].w;
  }
  __shared__ int s[1024];
  s[t] = sum;
  __syncthreads();
  for (int off = 1; off < 1024; off <<= 1) {
    int x = (t >= off) ? s[t - off] : 0;
    __syncthreads();
    s[t] += x;
    __syncthreads();
  }
  int run = s[t] - sum;               // exclusive base
  int4* r4 = (int4*)rowptr;
  int4* f4 = (int4*)fill;
#pragma unroll
  for (int k = 0; k < 13; ++k) {
    int i4 = i40 + k;
    if (i4 < (NN >> 2)) {
      int4 vv = v[k];
      int4 o;
      o.x = run;
      o.y = run + vv.x;
      o.z = o.y + vv.y;
      o.w = o.z + vv.z;
      run = o.w + vv.w;
      r4[i4] = o;
      f4[i4] = o;
    }
  }
  if (t == 0) rowptr[NN] = NE;
}

// ---- K3: fused edge projection + score (stores exp) + scatter ----
// Cross-iteration prefetch: ef row (raw) + src one iteration ahead, so the
// h[src] gather issues in the first instrs of each iteration. Scatter carry
// also writes srcs_sorted. No sched barriers (per-wave DS ordering suffices).
__global__ __launch_bounds__(256, 3) void k_edge_score_scatter(const float* __restrict__ ef,
                                                               const __bf16* __restrict__ WtE,
                                                               const __bf16* __restrict__ h,
                                                               const int* __restrict__ src,
                                                               const int* __restrict__ dst,
                                                               int* __restrict__ fill,
                                                               int* __restrict__ eids,
                                                               int* __restrict__ srcs,
                                                               float* __restrict__ expsc) {
  int tid = threadIdx.x;
  int w = tid >> 6, lane = tid & 63, q = lane >> 4, c = lane & 15;
  __shared__ float elds[4][16][132];
  const unsigned int* h2 = (const unsigned int*)h;

  bf16x8 bf[8][2];
#pragma unroll
  for (int nt = 0; nt < 8; ++nt)
#pragma unroll
    for (int ks = 0; ks < 2; ++ks)
      bf[nt][ks] = *(const bf16x8*)&WtE[(nt * 16 + c) * 64 + ks * 32 + q * 8];

  int el = lane >> 2;
  int head = lane & 3;

  // prologue: prefetch first iteration's ef row + src
  int it = blockIdx.x;
  float4 ra0, ra1, rb0, rb1;
  int sr = 0;
  {
    int ebase = it * 64 + w * 16;
    const float* arow = ef + (size_t)(ebase + c) * 64 + q * 8;
    ra0 = *(const float4*)arow;        ra1 = *(const float4*)(arow + 4);
    rb0 = *(const float4*)(arow + 32); rb1 = *(const float4*)(arow + 36);
    sr = src[ebase + el];
  }

  int L = 0;
  for (; it < 12500; ++L) {
    int ebase = it * 64 + w * 16;

    // h gather issues immediately (sr is register-resident)
    const uint4* hrow = (const uint4*)(h2 + (size_t)sr * 64 + head * 16);
    uint4 hv0 = hrow[0], hv1 = hrow[1], hv2 = hrow[2], hv3 = hrow[3];

    // scatter carry (blocks 0..624, L<5): eids + srcs_sorted
    if (L < 5) {
      int e_sc = (blockIdx.x * 5 + L) * 256 + tid;
      if (e_sc < NE) {
        int sval = src[e_sc];
        int p = atomicAdd(&fill[dst[e_sc]], 1);
        eids[p] = e_sc;
        srcs[p] = sval;
      }
    }

    // prefetch next iteration's ef row + src
    int itn = it + 768;
    float4 na0, na1, nb0, nb1;
    int srn = 0;
    if (itn < 12500) {
      int ebn = itn * 64 + w * 16;
      const float* arn = ef + (size_t)(ebn + c) * 64 + q * 8;
      na0 = *(const float4*)arn;        na1 = *(const float4*)(arn + 4);
      nb0 = *(const float4*)(arn + 32); nb1 = *(const float4*)(arn + 36);
      srn = src[ebn + el];
    }

    // current MFMA (af from registers prefetched last iteration)
    bf16x8 af0 = cvt8p(ra0, ra1);
    bf16x8 af1 = cvt8p(rb0, rb1);
    f32x4 acc[8];
#pragma unroll
    for (int nt = 0; nt < 8; ++nt) acc[nt] = (f32x4){0.f, 0.f, 0.f, 0.f};
#pragma unroll
    for (int nt = 0; nt < 8; ++nt) acc[nt] = mfma16(af0, bf[nt][0], acc[nt]);
#pragma unroll
    for (int nt = 0; nt < 8; ++nt) acc[nt] = mfma16(af1, bf[nt][1], acc[nt]);

    // fragment -> row-major LDS (per-wave slice; DS ops in-order per wave)
#pragma unroll
    for (int nt = 0; nt < 8; ++nt)
#pragma unroll
      for (int reg = 0; reg < 4; ++reg)
        elds[w][q * 4 + reg][nt * 16 + c] = acc[nt][reg];

    // lane-local dot: e-slice from LDS, h-slice from registers
    const float* erow = &elds[w][el][head * 32];
    float s = 0.f;
    union { unsigned int i; float f; } u0, u1;
#define DOT2(hd, ea, eb) \
    u0.i = (hd) << 16; u1.i = (hd) & 0xffff0000u; \
    s = fmaf(u0.f, (ea), s); s = fmaf(u1.f, (eb), s);
    {
      float4 e0 = *(const float4*)(erow +  0), e1 = *(const float4*)(erow +  4);
      float4 e2 = *(const float4*)(erow +  8), e3 = *(const float4*)(erow + 12);
      DOT2(hv0.x, e0.x, e0.y) DOT2(hv0.y, e0.z, e0.w)
      DOT2(hv0.z, e1.x, e1.y) DOT2(hv0.w, e1.z, e1.w)
      DOT2(hv1.x, e2.x, e2.y) DOT2(hv1.y, e2.z, e2.w)
      DOT2(hv1.z, e3.x, e3.y) DOT2(hv1.w, e3.z, e3.w)
    }
    {
      float4 e4 = *(const float4*)(erow + 16), e5 = *(const float4*)(erow + 20);
      float4 e6 = *(const float4*)(erow + 24), e7 = *(const float4*)(erow + 28);
      DOT2(hv2.x, e4.x, e4.y) DOT2(hv2.y, e4.z, e4.w)
      DOT2(hv2.z, e5.x, e5.y) DOT2(hv2.w, e5.z, e5.w)
      DOT2(hv3.x, e6.x, e6.y) DOT2(hv3.y, e6.z, e6.w)
      DOT2(hv3.z, e7.x, e7.y) DOT2(hv3.w, e7.z, e7.w)
    }
#undef DOT2

    s *= 0.17677669529663687f;        // 1/sqrt(32)
    float sv = s > 0.f ? s : 0.01f * s;
    // store exp(leaky(score)); sv is O(+-20) -> finite; ratios identical
    expsc[(size_t)ebase * 4 + lane] = __expf(sv);

    // rotate prefetched state
    if (itn < 12500) {
      ra0 = na0; ra1 = na1; rb0 = nb0; rb1 = nb1; sr = srn;
    }
    it = itn;
  }
}

// ---- K4: per-node softmax + aggregation (grid-stride @2048) ----
// Chunk-meta software pipeline: next chunk's eids/srcs/expsc issue during
// current chunk's CONS. srcs_sorted makes the src read coalesced and
// independent of eids -> h loads issue one gather-latency earlier.
__global__ __launch_bounds__(256) void k_aggregate(const int* __restrict__ rowptr,
                                                   const int* __restrict__ eids,
                                                   const int* __restrict__ srcs,
                                                   const float* __restrict__ expsc,
                                                   const __bf16* __restrict__ h,
                                                   float* __restrict__ out) {
  int w = threadIdx.x >> 6, lane = threadIdx.x & 63;
  int head = lane >> 4;
  int je = lane & 15;
  int hb = head << 4;
  const unsigned int* h2 = (const unsigned int*)h;

  for (int grp = blockIdx.x; grp < 12500; grp += gridDim.x) {
    int n = grp * 4 + w;                              // 12500*4 = 50000
    int s0 = rowptr[n], s1 = rowptr[n + 1];

    float l = 0.f, a0 = 0.f, a1 = 0.f;

    int c0 = s0;
    int nc = s1 - c0; if (nc > 16) nc = 16;
    int el = 0, srl = 0; float p = 0.f;
    if (je < nc) {
      el = eids[c0 + je];               // gather chain head (for expsc only)
      srl = srcs[c0 + je];              // coalesced, independent of eids
    }
    if (je < nc) p = expsc[(size_t)el * 4 + head];

    while (c0 < s1) {
      int c1 = c0 + 16;
      int nc2 = s1 - c1; if (nc2 > 16) nc2 = 16;

      // denominator butterfly over the 16 edge-slots of this head group
      float ps = p;
      ps += __shfl_xor(ps, 1, 64);
      ps += __shfl_xor(ps, 2, 64);
      ps += __shfl_xor(ps, 4, 64);
      ps += __shfl_xor(ps, 8, 64);
      l += ps;

      uint4 A, B, C, D;
#define LOADG(Dv, base) { int sr_; \
      sr_ = __shfl(srl, (base) + 0, 64); Dv.x = h2[(size_t)sr_ * 64 + lane]; \
      sr_ = __shfl(srl, (base) + 1, 64); Dv.y = h2[(size_t)sr_ * 64 + lane]; \
      sr_ = __shfl(srl, (base) + 2, 64); Dv.z = h2[(size_t)sr_ * 64 + lane]; \
      sr_ = __shfl(srl, (base) + 3, 64); Dv.w = h2[(size_t)sr_ * 64 + lane]; }
#define CONS(Dv, base) { float pj_; union { unsigned int i; float f; } u0_, u1_; \
      pj_ = __shfl(p, hb + (base) + 0, 64); u0_.i = Dv.x << 16; u1_.i = Dv.x & 0xffff0000u; a0 = fmaf(pj_, u0_.f, a0); a1 = fmaf(pj_, u1_.f, a1); \
      pj_ = __shfl(p, hb + (base) + 1, 64); u0_.i = Dv.y << 16; u1_.i = Dv.y & 0xffff0000u; a0 = fmaf(pj_, u0_.f, a0); a1 = fmaf(pj_, u1_.f, a1); \
      pj_ = __shfl(p, hb + (base) + 2, 64); u0_.i = Dv.z << 16; u1_.i = Dv.z & 0xffff0000u; a0 = fmaf(pj_, u0_.f, a0); a1 = fmaf(pj_, u1_.f, a1); \
      pj_ = __shfl(p, hb + (base) + 3, 64); u0_.i = Dv.w << 16; u1_.i = Dv.w & 0xffff0000u; a0 = fmaf(pj_, u0_.f, a0); a1 = fmaf(pj_, u1_.f, a1); }

      // issue all 16 h-row loads for the current chunk
      LOADG(A, 0); LOADG(B, 4); LOADG(C, 8); LOADG(D, 12);

      // prefetch next chunk meta (hides under CONS + next butterfly)
      int el2 = 0, srl2 = 0; float p2 = 0.f;
      if (je < nc2) {
        el2 = eids[c1 + je];
        srl2 = srcs[c1 + je];
      }
      if (je < nc2) p2 = expsc[(size_t)el2 * 4 + head];

      // consume current chunk
      CONS(A, 0); CONS(B, 4); CONS(C, 8); CONS(D, 12);
#undef LOADG
#undef CONS

      el = el2; srl = srl2; p = p2; c0 = c1;
    }
    float inv = (s1 > s0) ? 1.f / l : 0.f;
    float2 o; o.x = a0 * inv; o.y = a1 * inv;
    ((float2*)out)[(size_t)n * 64 + lane] = o;
  }
}

extern "C" void kernel_launch(void* const* d_in, const int* in_sizes, int n_in,
                              void* d_out, int out_size, void* d_ws, size_t ws_size,
                              hipStream_t stream) {
  const float* node_feat = (const float*)d_in[0];   // [NN,256] fp32
  const float* edge_feat = (const float*)d_in[1];   // [NE,64]  fp32
  const int*   src       = (const int*)d_in[2];
  const int*   dst       = (const int*)d_in[3];
  const float* W_node    = (const float*)d_in[4];   // [256,128] fp32
  const float* W_edge    = (const float*)d_in[5];   // [64,128]  fp32
  float* out             = (float*)d_out;           // [NN,128] fp32

  char* ws = (char*)d_ws;
  __bf16* h      = (__bf16*)(ws + 0);               // 12,800,000
  float*  expsc  = (float*) (ws + 12800000);        // 12,800,000
  int*    eids   = (int*)   (ws + 25600000);        //  3,200,000
  int*    deg    = (int*)   (ws + 28800000);        //    200,000
  int*    rowptr = (int*)   (ws + 29000192);        //    200,004
  int*    fill   = (int*)   (ws + 29200640);        //    200,000
  __bf16* WtN    = (__bf16*)(ws + 29402880);        //     65,536
  __bf16* WtE    = (__bf16*)(ws + 29468416);        //     16,384
  int*    srcs   = (int*)   (ws + 29484800);        //  3,200,000

  k_transpose_w       <<<160, 256, 0, stream>>>(W_node, W_edge, WtN, WtE, deg);
  k_node_proj_deg     <<<625, 256, 0, stream>>>(node_feat, WtN, h, dst, deg);
  k_scan_all          <<<1, 1024, 0, stream>>>(deg, rowptr, fill);
  k_edge_score_scatter<<<768, 256, 0, stream>>>(edge_feat, WtE, h, src, dst, fill, eids, srcs, expsc);
  k_aggregate         <<<2048, 256, 0, stream>>>(rowptr, eids, srcs, expsc, h, out);
}

// Round 9
// 469.357 us; speedup vs baseline: 3.9147x; 1.0182x over previous
//
#include <hip/hip_runtime.h>
#include <hip/hip_bf16.h>

// GIPA wide conv: h=XWn; e=EWe; score=leaky(dot_head(h[src],e)/sqrt(32));
// softmax over dst; out = segsum(h[src]*attn).
// R9: throughput fixes from R8 post-mortem.
//  - k_aggregate: 32-edge chunks (32 h-rows in flight, half the phases;
//    single chunk for ~all nodes at mean degree 16)
//  - k_node_proj: LDS-staged A-tile (kills 4x redundant nf reads across waves)
//  - es / scan / transpose unchanged from R8.
// 5 dispatches.

#define NN 50000
#define NE 800000

typedef __bf16 bf16x8 __attribute__((ext_vector_type(8)));
typedef float f32x4 __attribute__((ext_vector_type(4)));

static __device__ __forceinline__ f32x4 mfma16(bf16x8 a, bf16x8 b, f32x4 c) {
  return __builtin_amdgcn_mfma_f32_16x16x32_bf16(a, b, c, 0, 0, 0);
}

static __device__ __forceinline__ bf16x8 cvt8(const float* p) {
  float4 a = *(const float4*)p;
  float4 b = *(const float4*)(p + 4);
  bf16x8 r;
  r[0] = (__bf16)a.x; r[1] = (__bf16)a.y; r[2] = (__bf16)a.z; r[3] = (__bf16)a.w;
  r[4] = (__bf16)b.x; r[5] = (__bf16)b.y; r[6] = (__bf16)b.z; r[7] = (__bf16)b.w;
  return r;
}

static __device__ __forceinline__ bf16x8 cvt8p(float4 a, float4 b) {
  bf16x8 r;
  r[0] = (__bf16)a.x; r[1] = (__bf16)a.y; r[2] = (__bf16)a.z; r[3] = (__bf16)a.w;
  r[4] = (__bf16)b.x; r[5] = (__bf16)b.y; r[6] = (__bf16)b.z; r[7] = (__bf16)b.w;
  return r;
}

// ---- K0: transpose + fp32->bf16 weights, zero deg ----
__global__ __launch_bounds__(256) void k_transpose_w(const float* __restrict__ Wn,
                                                     const float* __restrict__ We,
                                                     __bf16* __restrict__ WtN,
                                                     __bf16* __restrict__ WtE,
                                                     int* __restrict__ deg) {
  int t = blockIdx.x * 256 + threadIdx.x;             // 160*256 = 40960 threads
  if (t < 128 * 256) {
    int col = t >> 8, k = t & 255;
    WtN[t] = (__bf16)Wn[k * 128 + col];
  } else {
    int o = t - 128 * 256;            // 0..8191
    int col = o >> 6, k = o & 63;
    WtE[o] = (__bf16)We[k * 128 + col];
  }
  for (int i = t; i < NN; i += 40960) deg[i] = 0;
}

// ---- K1: node projection + degree histogram, LDS-staged A-tile ----
// Block stages 16 nf rows (fp32->bf16) into LDS once; all 4 waves read their
// MFMA A-fragments from LDS (was: each wave re-read the same rows from HBM).
// Row pad 264: lane stride 528B -> 2-way bank alias (free).
__global__ __launch_bounds__(256) void k_node_proj_deg(const float* __restrict__ nf,
                                                       const __bf16* __restrict__ WtN,
                                                       __bf16* __restrict__ h,
                                                       const int* __restrict__ dst,
                                                       int* __restrict__ deg) {
  int tid = threadIdx.x;
  int w = tid >> 6, lane = tid & 63, q = lane >> 4, c = lane & 15;
  int colbase = w * 32;
  __shared__ __bf16 lds_a[16][264];

  bf16x8 bf[2][8];
#pragma unroll
  for (int nt = 0; nt < 2; ++nt)
#pragma unroll
    for (int ks = 0; ks < 8; ++ks)
      bf[nt][ks] = *(const bf16x8*)&WtN[(colbase + nt * 16 + c) * 256 + ks * 32 + q * 8];

  int r = tid >> 4, tt = tid & 15;    // staging map: 16 threads/row, 16 floats each

  for (int g = 0; g < 5; ++g) {
    int gi = blockIdx.x * 5 + g;
    int gbase = gi * 16;                              // exact: 625*5*16 = 50000
    int e_d = gi * 256 + tid;                         // exact: 625*5*256 = 800000
    int dv = dst[e_d];

    // stage 16 rows x 256 cols (coalesced 1KB per 16-thread row group)
    const float* srcp = nf + (size_t)(gbase + r) * 256 + tt * 16;
    float4 v0 = *(const float4*)(srcp);
    float4 v1 = *(const float4*)(srcp + 4);
    float4 v2 = *(const float4*)(srcp + 8);
    float4 v3 = *(const float4*)(srcp + 12);

    atomicAdd(&deg[dv], 1);           // hidden under the staging loads

    __bf16* dstp = &lds_a[r][tt * 16];
    dstp[ 0] = (__bf16)v0.x; dstp[ 1] = (__bf16)v0.y; dstp[ 2] = (__bf16)v0.z; dstp[ 3] = (__bf16)v0.w;
    dstp[ 4] = (__bf16)v1.x; dstp[ 5] = (__bf16)v1.y; dstp[ 6] = (__bf16)v1.z; dstp[ 7] = (__bf16)v1.w;
    dstp[ 8] = (__bf16)v2.x; dstp[ 9] = (__bf16)v2.y; dstp[10] = (__bf16)v2.z; dstp[11] = (__bf16)v2.w;
    dstp[12] = (__bf16)v3.x; dstp[13] = (__bf16)v3.y; dstp[14] = (__bf16)v3.z; dstp[15] = (__bf16)v3.w;
    __syncthreads();

    bf16x8 af[8];
#pragma unroll
    for (int ks = 0; ks < 8; ++ks)
      af[ks] = *(const bf16x8*)&lds_a[c][ks * 32 + q * 8];
    __syncthreads();                  // reads done; LDS reusable next g

    f32x4 acc0 = {0.f, 0.f, 0.f, 0.f}, acc1 = acc0;
#pragma unroll
    for (int ks = 0; ks < 8; ++ks) {
      acc0 = mfma16(af[ks], bf[0][ks], acc0);
      acc1 = mfma16(af[ks], bf[1][ks], acc1);
    }
#pragma unroll
    for (int reg = 0; reg < 4; ++reg) {
      int node = gbase + q * 4 + reg;
      h[(size_t)node * 128 + colbase + c]      = (__bf16)acc0[reg];
      h[(size_t)node * 128 + colbase + 16 + c] = (__bf16)acc1[reg];
    }
  }
}

// ---- K2: single-block exclusive scan (1024 thr, 13 int4 each) ----
__global__ __launch_bounds__(1024) void k_scan_all(const int* __restrict__ deg,
                                                   int* __restrict__ rowptr,
                                                   int* __restrict__ fill) {
  int t = threadIdx.x;
  const int4* d4 = (const int4*)deg;
  int i40 = t * 13;                   // 1024*13 = 13312 >= 12500 = NN/4
  int4 v[13];
#pragma unroll
  for (int k = 0; k < 13; ++k) {
    int i4 = i40 + k;
    if (i4 < (NN >> 2)) v[k] = d4[i4];
  }
  int sum = 0;
#pragma unroll
  for (int k = 0; k < 13; ++k) {
    int i4 = i40 + k;
    if (i4 < (NN >> 2)) sum += v[k].x + v[k].y + v[k].z + v[k].w;
  }
  __shared__ int s[1024];
  s[t] = sum;
  __syncthreads();
  for (int off = 1; off < 1024; off <<= 1) {
    int x = (t >= off) ? s[t - off] : 0;
    __syncthreads();
    s[t] += x;
    __syncthreads();
  }
  int run = s[t] - sum;               // exclusive base
  int4* r4 = (int4*)rowptr;
  int4* f4 = (int4*)fill;
#pragma unroll
  for (int k = 0; k < 13; ++k) {
    int i4 = i40 + k;
    if (i4 < (NN >> 2)) {
      int4 vv = v[k];
      int4 o;
      o.x = run;
      o.y = run + vv.x;
      o.z = o.y + vv.y;
      o.w = o.z + vv.z;
      run = o.w + vv.w;
      r4[i4] = o;
      f4[i4] = o;
    }
  }
  if (t == 0) rowptr[NN] = NE;
}

// ---- K3: fused edge projection + score (stores exp) + scatter ----
__global__ __launch_bounds__(256, 3) void k_edge_score_scatter(const float* __restrict__ ef,
                                                               const __bf16* __restrict__ WtE,
                                                               const __bf16* __restrict__ h,
                                                               const int* __restrict__ src,
                                                               const int* __restrict__ dst,
                                                               int* __restrict__ fill,
                                                               int* __restrict__ eids,
                                                               int* __restrict__ srcs,
                                                               float* __restrict__ expsc) {
  int tid = threadIdx.x;
  int w = tid >> 6, lane = tid & 63, q = lane >> 4, c = lane & 15;
  __shared__ float elds[4][16][132];
  const unsigned int* h2 = (const unsigned int*)h;

  bf16x8 bf[8][2];
#pragma unroll
  for (int nt = 0; nt < 8; ++nt)
#pragma unroll
    for (int ks = 0; ks < 2; ++ks)
      bf[nt][ks] = *(const bf16x8*)&WtE[(nt * 16 + c) * 64 + ks * 32 + q * 8];

  int el = lane >> 2;
  int head = lane & 3;

  // prologue: prefetch first iteration's ef row + src
  int it = blockIdx.x;
  float4 ra0, ra1, rb0, rb1;
  int sr = 0;
  {
    int ebase = it * 64 + w * 16;
    const float* arow = ef + (size_t)(ebase + c) * 64 + q * 8;
    ra0 = *(const float4*)arow;        ra1 = *(const float4*)(arow + 4);
    rb0 = *(const float4*)(arow + 32); rb1 = *(const float4*)(arow + 36);
    sr = src[ebase + el];
  }

  int L = 0;
  for (; it < 12500; ++L) {
    int ebase = it * 64 + w * 16;

    // h gather issues immediately (sr is register-resident)
    const uint4* hrow = (const uint4*)(h2 + (size_t)sr * 64 + head * 16);
    uint4 hv0 = hrow[0], hv1 = hrow[1], hv2 = hrow[2], hv3 = hrow[3];

    // scatter carry (blocks 0..624, L<5): eids + srcs_sorted
    if (L < 5) {
      int e_sc = (blockIdx.x * 5 + L) * 256 + tid;
      if (e_sc < NE) {
        int sval = src[e_sc];
        int p = atomicAdd(&fill[dst[e_sc]], 1);
        eids[p] = e_sc;
        srcs[p] = sval;
      }
    }

    // prefetch next iteration's ef row + src
    int itn = it + 768;
    float4 na0, na1, nb0, nb1;
    int srn = 0;
    if (itn < 12500) {
      int ebn = itn * 64 + w * 16;
      const float* arn = ef + (size_t)(ebn + c) * 64 + q * 8;
      na0 = *(const float4*)arn;        na1 = *(const float4*)(arn + 4);
      nb0 = *(const float4*)(arn + 32); nb1 = *(const float4*)(arn + 36);
      srn = src[ebn + el];
    }

    // current MFMA (af from registers prefetched last iteration)
    bf16x8 af0 = cvt8p(ra0, ra1);
    bf16x8 af1 = cvt8p(rb0, rb1);
    f32x4 acc[8];
#pragma unroll
    for (int nt = 0; nt < 8; ++nt) acc[nt] = (f32x4){0.f, 0.f, 0.f, 0.f};
#pragma unroll
    for (int nt = 0; nt < 8; ++nt) acc[nt] = mfma16(af0, bf[nt][0], acc[nt]);
#pragma unroll
    for (int nt = 0; nt < 8; ++nt) acc[nt] = mfma16(af1, bf[nt][1], acc[nt]);

    // fragment -> row-major LDS (per-wave slice; DS ops in-order per wave)
#pragma unroll
    for (int nt = 0; nt < 8; ++nt)
#pragma unroll
      for (int reg = 0; reg < 4; ++reg)
        elds[w][q * 4 + reg][nt * 16 + c] = acc[nt][reg];

    // lane-local dot: e-slice from LDS, h-slice from registers
    const float* erow = &elds[w][el][head * 32];
    float s = 0.f;
    union { unsigned int i; float f; } u0, u1;
#define DOT2(hd, ea, eb) \
    u0.i = (hd) << 16; u1.i = (hd) & 0xffff0000u; \
    s = fmaf(u0.f, (ea), s); s = fmaf(u1.f, (eb), s);
    {
      float4 e0 = *(const float4*)(erow +  0), e1 = *(const float4*)(erow +  4);
      float4 e2 = *(const float4*)(erow +  8), e3 = *(const float4*)(erow + 12);
      DOT2(hv0.x, e0.x, e0.y) DOT2(hv0.y, e0.z, e0.w)
      DOT2(hv0.z, e1.x, e1.y) DOT2(hv0.w, e1.z, e1.w)
      DOT2(hv1.x, e2.x, e2.y) DOT2(hv1.y, e2.z, e2.w)
      DOT2(hv1.z, e3.x, e3.y) DOT2(hv1.w, e3.z, e3.w)
    }
    {
      float4 e4 = *(const float4*)(erow + 16), e5 = *(const float4*)(erow + 20);
      float4 e6 = *(const float4*)(erow + 24), e7 = *(const float4*)(erow + 28);
      DOT2(hv2.x, e4.x, e4.y) DOT2(hv2.y, e4.z, e4.w)
      DOT2(hv2.z, e5.x, e5.y) DOT2(hv2.w, e5.z, e5.w)
      DOT2(hv3.x, e6.x, e6.y) DOT2(hv3.y, e6.z, e6.w)
      DOT2(hv3.z, e7.x, e7.y) DOT2(hv3.w, e7.z, e7.w)
    }
#undef DOT2

    s *= 0.17677669529663687f;        // 1/sqrt(32)
    float sv = s > 0.f ? s : 0.01f * s;
    // store exp(leaky(score)); sv is O(+-20) -> finite; ratios identical
    expsc[(size_t)ebase * 4 + lane] = __expf(sv);

    // rotate prefetched state
    if (itn < 12500) {
      ra0 = na0; ra1 = na1; rb0 = nb0; rb1 = nb1; sr = srn;
    }
    it = itn;
  }
}

// ---- K4: per-node softmax + aggregation (grid-stride @2048) ----
// 32-edge chunks: lane = (head, je) with je covering edge slots {je, je+16}.
// 32 h-row loads in flight per chunk; one butterfly per 32 edges; meta for
// next chunk prefetched under loads. Pads: srl=0 (valid row), p=0.
__global__ __launch_bounds__(256) void k_aggregate(const int* __restrict__ rowptr,
                                                   const int* __restrict__ eids,
                                                   const int* __restrict__ srcs,
                                                   const float* __restrict__ expsc,
                                                   const __bf16* __restrict__ h,
                                                   float* __restrict__ out) {
  int w = threadIdx.x >> 6, lane = threadIdx.x & 63;
  int head = lane >> 4;
  int je = lane & 15;
  int hb = head << 4;
  const unsigned int* h2 = (const unsigned int*)h;

  for (int grp = blockIdx.x; grp < 12500; grp += gridDim.x) {
    int n = grp * 4 + w;                              // 12500*4 = 50000
    int s0 = rowptr[n], s1 = rowptr[n + 1];

    float l = 0.f, a0 = 0.f, a1 = 0.f;

    int c0 = s0;
    int nc = s1 - c0; if (nc > 32) nc = 32;
    int srlL = 0, srlH = 0, elL = 0, elH = 0;
    float pL = 0.f, pH = 0.f;
    if (je < nc)      { elL = eids[c0 + je];      srlL = srcs[c0 + je]; }
    if (je + 16 < nc) { elH = eids[c0 + je + 16]; srlH = srcs[c0 + je + 16]; }
    if (je < nc)      pL = expsc[(size_t)elL * 4 + head];
    if (je + 16 < nc) pH = expsc[(size_t)elH * 4 + head];

    while (c0 < s1) {
      int c1 = c0 + 32;
      int nc2 = s1 - c1; if (nc2 > 32) nc2 = 32;

      // denominator: sum over all 32 slots (lo+hi folded before butterfly)
      float ps = pL + pH;
      ps += __shfl_xor(ps, 1, 64);
      ps += __shfl_xor(ps, 2, 64);
      ps += __shfl_xor(ps, 4, 64);
      ps += __shfl_xor(ps, 8, 64);
      l += ps;

      uint4 A, B, C, D, E, F, G, H;
#define LOADG(Dv, S, base) { int sr_; \
      sr_ = __shfl(S, (base) + 0, 64); Dv.x = h2[(size_t)sr_ * 64 + lane]; \
      sr_ = __shfl(S, (base) + 1, 64); Dv.y = h2[(size_t)sr_ * 64 + lane]; \
      sr_ = __shfl(S, (base) + 2, 64); Dv.z = h2[(size_t)sr_ * 64 + lane]; \
      sr_ = __shfl(S, (base) + 3, 64); Dv.w = h2[(size_t)sr_ * 64 + lane]; }
#define CONS(Dv, P, base) { float pj_; union { unsigned int i; float f; } u0_, u1_; \
      pj_ = __shfl(P, hb + (base) + 0, 64); u0_.i = Dv.x << 16; u1_.i = Dv.x & 0xffff0000u; a0 = fmaf(pj_, u0_.f, a0); a1 = fmaf(pj_, u1_.f, a1); \
      pj_ = __shfl(P, hb + (base) + 1, 64); u0_.i = Dv.y << 16; u1_.i = Dv.y & 0xffff0000u; a0 = fmaf(pj_, u0_.f, a0); a1 = fmaf(pj_, u1_.f, a1); \
      pj_ = __shfl(P, hb + (base) + 2, 64); u0_.i = Dv.z << 16; u1_.i = Dv.z & 0xffff0000u; a0 = fmaf(pj_, u0_.f, a0); a1 = fmaf(pj_, u1_.f, a1); \
      pj_ = __shfl(P, hb + (base) + 3, 64); u0_.i = Dv.w << 16; u1_.i = Dv.w & 0xffff0000u; a0 = fmaf(pj_, u0_.f, a0); a1 = fmaf(pj_, u1_.f, a1); }

      // issue all 32 h-row loads for the current chunk
      LOADG(A, srlL, 0); LOADG(B, srlL, 4); LOADG(C, srlL, 8); LOADG(D, srlL, 12);
      LOADG(E, srlH, 0); LOADG(F, srlH, 4); LOADG(G, srlH, 8); LOADG(H, srlH, 12);

      // prefetch next chunk meta (hides under the 32 loads)
      int srlL2 = 0, srlH2 = 0, elL2 = 0, elH2 = 0;
      float pL2 = 0.f, pH2 = 0.f;
      if (c1 < s1) {
        if (je < nc2)      { elL2 = eids[c1 + je];      srlL2 = srcs[c1 + je]; }
        if (je + 16 < nc2) { elH2 = eids[c1 + je + 16]; srlH2 = srcs[c1 + je + 16]; }
        if (je < nc2)      pL2 = expsc[(size_t)elL2 * 4 + head];
        if (je + 16 < nc2) pH2 = expsc[(size_t)elH2 * 4 + head];
      }

      // consume current chunk (edges 0..15 lo, 16..31 hi)
      CONS(A, pL, 0); CONS(B, pL, 4); CONS(C, pL, 8); CONS(D, pL, 12);
      CONS(E, pH, 0); CONS(F, pH, 4); CONS(G, pH, 8); CONS(H, pH, 12);
#undef LOADG
#undef CONS

      srlL = srlL2; srlH = srlH2; pL = pL2; pH = pH2; c0 = c1;
    }
    float inv = (s1 > s0) ? 1.f / l : 0.f;
    float2 o; o.x = a0 * inv; o.y = a1 * inv;
    ((float2*)out)[(size_t)n * 64 + lane] = o;
  }
}

extern "C" void kernel_launch(void* const* d_in, const int* in_sizes, int n_in,
                              void* d_out, int out_size, void* d_ws, size_t ws_size,
                              hipStream_t stream) {
  const float* node_feat = (const float*)d_in[0];   // [NN,256] fp32
  const float* edge_feat = (const float*)d_in[1];   // [NE,64]  fp32
  const int*   src       = (const int*)d_in[2];
  const int*   dst       = (const int*)d_in[3];
  const float* W_node    = (const float*)d_in[4];   // [256,128] fp32
  const float* W_edge    = (const float*)d_in[5];   // [64,128]  fp32
  float* out             = (float*)d_out;           // [NN,128] fp32

  char* ws = (char*)d_ws;
  __bf16* h      = (__bf16*)(ws + 0);               // 12,800,000
  float*  expsc  = (float*) (ws + 12800000);        // 12,800,000
  int*    eids   = (int*)   (ws + 25600000);        //  3,200,000
  int*    deg    = (int*)   (ws + 28800000);        //    200,000
  int*    rowptr = (int*)   (ws + 29000192);        //    200,004
  int*    fill   = (int*)   (ws + 29200640);        //    200,000
  __bf16* WtN    = (__bf16*)(ws + 29402880);        //     65,536
  __bf16* WtE    = (__bf16*)(ws + 29468416);        //     16,384
  int*    srcs   = (int*)   (ws + 29484800);        //  3,200,000

  k_transpose_w       <<<160, 256, 0, stream>>>(W_node, W_edge, WtN, WtE, deg);
  k_node_proj_deg     <<<625, 256, 0, stream>>>(node_feat, WtN, h, dst, deg);
  k_scan_all          <<<1, 1024, 0, stream>>>(deg, rowptr, fill);
  k_edge_score_scatter<<<768, 256, 0, stream>>>(edge_feat, WtE, h, src, dst, fill, eids, srcs, expsc);
  k_aggregate         <<<2048, 256, 0, stream>>>(rowptr, eids, srcs, expsc, h, out);
}